// Round 4
// baseline (20626.489 us; speedup 1.0000x reference)
//
#include <hip/hip_runtime.h>
#include <hip/hip_bf16.h>
#include <hip/hip_cooperative_groups.h>

namespace cg = cooperative_groups;

// ScalarBorn: 4th-order FD scalar wave + Born scattering with CPML, MI355X.
// R4: single cooperative kernel, 300-step internal loop, ONE grid.sync/step.
// psi double-buffered + halo-recomputed so pass1/pass2 fuse without a 2nd sync.

constexpr int NYX  = 400;
constexpr int NS   = 4;
constexpr int NREC = 100;
constexpr int NT   = 300;
constexpr int PAD  = 22;
constexpr int NP   = 444;
constexpr int NP2  = NP * NP;          // 197136
constexpr int SNP2 = NS * NP2;         // 788544
constexpr float DT    = 0.0005f;
constexpr float INVH  = 0.2f;          // 1/DX
constexpr float INVH2 = 0.04f;         // 1/DX^2
constexpr float C1A = 1.0f / 12.0f;
constexpr float C1B = 2.0f / 3.0f;
constexpr float C2A = -1.0f / 12.0f;
constexpr float C2B = 4.0f / 3.0f;
constexpr float C2C = -2.5f;

__device__ __align__(16) float g_wb[2][SNP2];      // bg field ping-pong
__device__ __align__(16) float g_ws[2][SNP2];      // scattered field ping-pong
__device__ __align__(16) float g_psi[2][4][SNP2];  // [buf][py_b,px_b,py_s,px_s]
__device__ __align__(16) float g_zeta[4][SNP2];    // [zy_b,zx_b,zy_s,zx_s]
__device__ float g_v2dt2[NP2];
__device__ float g_bscale[NP2];
__device__ float g_pa[NP];
__device__ float g_pb[NP];
__device__ float g_fbg[NT * NS];
__device__ float g_fsc[NT * NS];
__device__ int   g_spos[2 * NS];
__device__ int   g_mode;               // 1 = bf16 io, 0 = f32 io

__device__ __forceinline__ int clampi(int v, int lo, int hi) {
    return v < lo ? lo : (v > hi ? hi : v);
}
__device__ __forceinline__ float in_ld(const void* p, int i) {
    if (g_mode) return __bfloat162float(((const __hip_bfloat16*)p)[i]);
    return ((const float*)p)[i];
}
__device__ __forceinline__ void out_st(void* p, int i, float v) {
    if (g_mode) ((__hip_bfloat16*)p)[i] = __float2bfloat16(v);
    else        ((float*)p)[i] = v;
}
__device__ __forceinline__ float ld(const float* w, int y, int x) {
    if ((unsigned)y >= (unsigned)NP || (unsigned)x >= (unsigned)NP) return 0.f;
    return w[y * NP + x];
}

__global__ void detect_mode(const void* vptr) {
    if (threadIdx.x == 0 && blockIdx.x == 0) {
        const __hip_bfloat16* p = (const __hip_bfloat16*)vptr;
        int ok = 1;
        for (int i = 0; i < 32; i += 2) {
            float f = __bfloat162float(p[i]);
            if (!(f >= 1000.f && f <= 3000.f)) ok = 0;
        }
        g_mode = ok;
    }
}

__global__ void zero_state() {
    int i = blockIdx.x * blockDim.x + threadIdx.x;
    if (i >= NP2) return;                 // SNP2/4 float4s per array == NP2
    float4 z = make_float4(0.f, 0.f, 0.f, 0.f);
    ((float4*)g_wb[0])[i] = z;  ((float4*)g_wb[1])[i] = z;
    ((float4*)g_ws[0])[i] = z;  ((float4*)g_ws[1])[i] = z;
    #pragma unroll
    for (int b = 0; b < 2; ++b)
        #pragma unroll
        for (int k = 0; k < 4; ++k) ((float4*)g_psi[b][k])[i] = z;
    #pragma unroll
    for (int k = 0; k < 4; ++k) ((float4*)g_zeta[k])[i] = z;
}

__global__ void prep_pad(const void* __restrict__ v, const void* __restrict__ sc) {
    int i = blockIdx.x * blockDim.x + threadIdx.x;
    if (i >= NP2) return;
    int y = i / NP, x = i % NP;
    int vy = clampi(y - PAD, 0, NYX - 1);
    int vx = clampi(x - PAD, 0, NYX - 1);
    float vv = in_ld(v, vy * NYX + vx);
    float vd = vv * DT;
    g_v2dt2[i] = vd * vd;
    float s = 0.f;
    if (y >= PAD && y < PAD + NYX && x >= PAD && x < PAD + NYX)
        s = in_ld(sc, (y - PAD) * NYX + (x - PAD));
    g_bscale[i] = 2.f * vv * s * DT * DT;
    if (i < NP) {
        float fi = (float)i;
        float f1 = fminf(fmaxf((22.f - fi) * 0.05f, 0.f), 1.f);
        float f2 = fminf(fmaxf((fi - 421.f) * 0.05f, 0.f), 1.f);
        float frac = fmaxf(f1, f2);
        float sigma = 259.0408229f * frac * frac;
        const float alpha = 78.53981634f;
        float a = expf(-(sigma + alpha) * DT);
        g_pa[i] = a;
        g_pb[i] = (sigma > 0.f) ? sigma / (sigma + alpha) * (a - 1.f) : 0.f;
    }
}

__global__ void prep_src(const void* __restrict__ amp, const int* __restrict__ sloc,
                         const void* __restrict__ v, const void* __restrict__ sc) {
    int i = blockIdx.x * blockDim.x + threadIdx.x;
    if (i >= NT * NS) return;
    int s = i % NS, t = i / NS;
    int ly = clampi(sloc[s * 2 + 0], 0, NYX - 1);
    int lx = clampi(sloc[s * 2 + 1], 0, NYX - 1);
    float a  = in_ld(amp, s * NT + t);
    float vv = in_ld(v,  ly * NYX + lx);
    float ss = in_ld(sc, ly * NYX + lx);
    g_fbg[i] = -a * vv * vv * DT * DT;
    g_fsc[i] = -2.f * a * vv * ss * DT * DT;
    if (i < NS) {
        g_spos[2 * i]     = ly + PAD;
        g_spos[2 * i + 1] = lx + PAD;
    }
}

// recompute dpsi_y at (y,x): psi_new at y+{-2,-1,1,2} rebuilt from psi_old + w.
__device__ __forceinline__ void dpsi_y(const float* wb, const float* wsc,
                                       const float* pob, const float* pos,
                                       int y, int x, float& dpb, float& dps) {
    const int off[4] = {-2, -1, 1, 2};
    float pnb[4], pns[4];
    #pragma unroll
    for (int k = 0; k < 4; ++k) {
        int yy = y + off[k];
        float pbv = ((unsigned)yy < (unsigned)NP) ? g_pb[yy] : 0.f;
        float b_ = 0.f, s_ = 0.f;
        if (pbv != 0.f) {
            float pav = g_pa[yy];
            float dwb = (C1A * ld(wb, yy - 2, x) - C1B * ld(wb, yy - 1, x)
                       + C1B * ld(wb, yy + 1, x) - C1A * ld(wb, yy + 2, x)) * INVH;
            float dws = (C1A * ld(wsc, yy - 2, x) - C1B * ld(wsc, yy - 1, x)
                       + C1B * ld(wsc, yy + 1, x) - C1A * ld(wsc, yy + 2, x)) * INVH;
            b_ = pav * pob[yy * NP + x] + pbv * dwb;
            s_ = pav * pos[yy * NP + x] + pbv * dws;
        }
        pnb[k] = b_; pns[k] = s_;
    }
    dpb = (C1A * pnb[0] - C1B * pnb[1] + C1B * pnb[2] - C1A * pnb[3]) * INVH;
    dps = (C1A * pns[0] - C1B * pns[1] + C1B * pns[2] - C1A * pns[3]) * INVH;
}

__device__ __forceinline__ void dpsi_x(const float* wb, const float* wsc,
                                       const float* pob, const float* pos,
                                       int y, int x, float& dpb, float& dps) {
    const int off[4] = {-2, -1, 1, 2};
    float pnb[4], pns[4];
    #pragma unroll
    for (int k = 0; k < 4; ++k) {
        int xx = x + off[k];
        float pbv = ((unsigned)xx < (unsigned)NP) ? g_pb[xx] : 0.f;
        float b_ = 0.f, s_ = 0.f;
        if (pbv != 0.f) {
            float pav = g_pa[xx];
            float dwb = (C1A * ld(wb, y, xx - 2) - C1B * ld(wb, y, xx - 1)
                       + C1B * ld(wb, y, xx + 1) - C1A * ld(wb, y, xx + 2)) * INVH;
            float dws = (C1A * ld(wsc, y, xx - 2) - C1B * ld(wsc, y, xx - 1)
                       + C1B * ld(wsc, y, xx + 1) - C1A * ld(wsc, y, xx + 2)) * INVH;
            b_ = pav * pob[y * NP + xx] + pbv * dwb;
            s_ = pav * pos[y * NP + xx] + pbv * dws;
        }
        pnb[k] = b_; pns[k] = s_;
    }
    dpb = (C1A * pnb[0] - C1B * pnb[1] + C1B * pnb[2] - C1A * pnb[3]) * INVH;
    dps = (C1A * pns[0] - C1B * pns[1] + C1B * pns[2] - C1A * pns[3]) * INVH;
}

__global__ void __launch_bounds__(448, 4)
timeloop(const int* __restrict__ rloc, const int* __restrict__ rbloc,
         void* __restrict__ out) {
    cg::grid_group grid = cg::this_grid();
    const int tid = threadIdx.x;
    const int nb  = gridDim.x;

    for (int t = 0; t < NT; ++t) {
        const int cur = t & 1, nxt = cur ^ 1;

        // record step t-1 (field currently in buffer cur), one block
        if (t > 0 && blockIdx.x == nb - 1) {
            for (int k = tid; k < 2 * NS * NREC; k += blockDim.x) {
                bool isbg = k < NS * NREC;
                int  j = isbg ? k : k - NS * NREC;
                int  s = j / NREC, r = j % NREC;
                const int* rl = isbg ? rbloc : rloc;
                int ry = clampi(rl[(s * NREC + r) * 2 + 0], 0, NYX - 1) + PAD;
                int rx = clampi(rl[(s * NREC + r) * 2 + 1], 0, NYX - 1) + PAD;
                const float* w = isbg ? g_wb[cur] : g_ws[cur];
                float val = w[s * NP2 + ry * NP + rx];
                int base = isbg ? (2 * SNP2) : (2 * SNP2 + NS * NREC * NT);
                out_st(out, base + (s * NREC + r) * NT + (t - 1), val);
            }
        }

        const int x = tid;
        if (x < NP) {
            for (int rr = blockIdx.x; rr < NS * NP; rr += nb) {
                const int s = rr & 3;
                const int y = rr >> 2;
                const int yx  = y * NP + x;
                const int idx = s * NP2 + yx;
                const float* wb  = g_wb[cur] + s * NP2;
                const float* wsc = g_ws[cur] + s * NP2;

                float wc_b = wb[yx];
                float wc_s = wsc[yx];
                float d2y_b = (C2A * (ld(wb, y - 2, x) + ld(wb, y + 2, x))
                             + C2B * (ld(wb, y - 1, x) + ld(wb, y + 1, x)) + C2C * wc_b) * INVH2;
                float d2x_b = (C2A * (ld(wb, y, x - 2) + ld(wb, y, x + 2))
                             + C2B * (ld(wb, y, x - 1) + ld(wb, y, x + 1)) + C2C * wc_b) * INVH2;
                float d2y_s = (C2A * (ld(wsc, y - 2, x) + ld(wsc, y + 2, x))
                             + C2B * (ld(wsc, y - 1, x) + ld(wsc, y + 1, x)) + C2C * wc_s) * INVH2;
                float d2x_s = (C2A * (ld(wsc, y, x - 2) + ld(wsc, y, x + 2))
                             + C2B * (ld(wsc, y, x - 1) + ld(wsc, y, x + 1)) + C2C * wc_s) * INVH2;

                const float pby = g_pb[y], pbx = g_pb[x];

                float dpy_b = 0.f, dpy_s = 0.f, dpx_b = 0.f, dpx_s = 0.f;
                if (y <= 23 || y >= 420)
                    dpsi_y(wb, wsc, g_psi[cur][0] + s * NP2, g_psi[cur][2] + s * NP2,
                           y, x, dpy_b, dpy_s);
                if (x <= 23 || x >= 420)
                    dpsi_x(wb, wsc, g_psi[cur][1] + s * NP2, g_psi[cur][3] + s * NP2,
                           y, x, dpx_b, dpx_s);

                // own psi update -> write to next buffer (only frame points)
                if (pby != 0.f) {
                    float pay = g_pa[y];
                    float dwb = (C1A * ld(wb, y - 2, x) - C1B * ld(wb, y - 1, x)
                               + C1B * ld(wb, y + 1, x) - C1A * ld(wb, y + 2, x)) * INVH;
                    float dws = (C1A * ld(wsc, y - 2, x) - C1B * ld(wsc, y - 1, x)
                               + C1B * ld(wsc, y + 1, x) - C1A * ld(wsc, y + 2, x)) * INVH;
                    g_psi[nxt][0][idx] = pay * g_psi[cur][0][idx] + pby * dwb;
                    g_psi[nxt][2][idx] = pay * g_psi[cur][2][idx] + pby * dws;
                }
                if (pbx != 0.f) {
                    float pax = g_pa[x];
                    float dwb = (C1A * ld(wb, y, x - 2) - C1B * ld(wb, y, x - 1)
                               + C1B * ld(wb, y, x + 1) - C1A * ld(wb, y, x + 2)) * INVH;
                    float dws = (C1A * ld(wsc, y, x - 2) - C1B * ld(wsc, y, x - 1)
                               + C1B * ld(wsc, y, x + 1) - C1A * ld(wsc, y, x + 2)) * INVH;
                    g_psi[nxt][1][idx] = pax * g_psi[cur][1][idx] + pbx * dwb;
                    g_psi[nxt][3][idx] = pax * g_psi[cur][3][idx] + pbx * dws;
                }

                // zeta (in-place, own point only)
                float zy_b = 0.f, zy_s = 0.f, zx_b = 0.f, zx_s = 0.f;
                if (pby != 0.f) {
                    float pay = g_pa[y];
                    zy_b = pay * g_zeta[0][idx] + pby * (d2y_b + dpy_b);  g_zeta[0][idx] = zy_b;
                    zy_s = pay * g_zeta[2][idx] + pby * (d2y_s + dpy_s);  g_zeta[2][idx] = zy_s;
                }
                if (pbx != 0.f) {
                    float pax = g_pa[x];
                    zx_b = pax * g_zeta[1][idx] + pbx * (d2x_b + dpx_b);  g_zeta[1][idx] = zx_b;
                    zx_s = pax * g_zeta[3][idx] + pbx * (d2x_s + dpx_s);  g_zeta[3][idx] = zx_s;
                }

                float lap_b = d2y_b + d2x_b + dpy_b + dpx_b + zy_b + zx_b;
                float lap_s = d2y_s + d2x_s + dpy_s + dpx_s + zy_s + zx_s;
                float v2 = g_v2dt2[yx];
                float* wpb = g_wb[nxt] + s * NP2;   // holds w_{t-1}, becomes w_{t+1}
                float* wps = g_ws[nxt] + s * NP2;
                float wn_b = v2 * lap_b + 2.f * wc_b - wpb[yx];
                float wn_s = v2 * lap_s + 2.f * wc_s - wps[yx] + g_bscale[yx] * lap_b;
                if (y == g_spos[2 * s] && x == g_spos[2 * s + 1]) {
                    wn_b += g_fbg[t * NS + s];
                    wn_s += g_fsc[t * NS + s];
                }
                wpb[yx] = wn_b;
                wps[yx] = wn_s;
            }
        }
        grid.sync();
    }
}

__global__ void finalize(const int* __restrict__ rloc, const int* __restrict__ rbloc,
                         void* __restrict__ out) {
    int i = blockIdx.x * blockDim.x + threadIdx.x;
    const float* wb0 = g_wb[0];   // NT even: newest field in buffer 0
    const float* ws0 = g_ws[0];
    if (i < SNP2) {
        out_st(out, i,        wb0[i]);
        out_st(out, SNP2 + i, ws0[i]);
    }
    if (i < 2 * NS * NREC) {      // record last step (t = NT-1)
        bool isbg = i < NS * NREC;
        int k = isbg ? i : i - NS * NREC;
        int s = k / NREC, r = k % NREC;
        const int* rl = isbg ? rbloc : rloc;
        int ry = clampi(rl[(s * NREC + r) * 2 + 0], 0, NYX - 1) + PAD;
        int rx = clampi(rl[(s * NREC + r) * 2 + 1], 0, NYX - 1) + PAD;
        const float* w = isbg ? wb0 : ws0;
        float val = w[s * NP2 + ry * NP + rx];
        int base = isbg ? (2 * SNP2) : (2 * SNP2 + NS * NREC * NT);
        out_st(out, base + (s * NREC + r) * NT + (NT - 1), val);
    }
}

extern "C" void kernel_launch(void* const* d_in, const int* in_sizes, int n_in,
                              void* d_out, int out_size, void* d_ws, size_t ws_size,
                              hipStream_t stream) {
    const void* v   = d_in[0];
    const void* sc  = d_in[1];
    const void* amp = d_in[2];
    const int* sloc  = (const int*)d_in[3];
    const int* rloc  = (const int*)d_in[4];
    const int* rbloc = (const int*)d_in[5];

    detect_mode<<<1, 64, 0, stream>>>(v);
    zero_state<<<(NP2 + 255) / 256, 256, 0, stream>>>();
    prep_pad<<<(NP2 + 255) / 256, 256, 0, stream>>>(v, sc);
    prep_src<<<(NT * NS + 255) / 256, 256, 0, stream>>>(amp, sloc, v, sc);

    int maxb = 0;
    hipOccupancyMaxActiveBlocksPerMultiprocessor(&maxb, timeloop, 448, 0);
    if (maxb < 1) maxb = 1;
    int grid = maxb * 256;                 // 256 CUs on MI355X
    if (grid > NS * NP) grid = NS * NP;

    void* args[] = {(void*)&rloc, (void*)&rbloc, (void*)&d_out};
    hipLaunchCooperativeKernel((const void*)timeloop, dim3(grid), dim3(448),
                               args, 0, stream);

    finalize<<<(SNP2 + 255) / 256, 256, 0, stream>>>(rloc, rbloc, d_out);
}

// Round 5
// 8699.762 us; speedup vs baseline: 2.3709x; 2.3709x over previous
//
#include <hip/hip_runtime.h>
#include <hip/hip_bf16.h>

// ScalarBorn: 4th-order FD scalar wave + Born scattering with CPML, MI355X.
// R5: ONE fused kernel per timestep (300 stencil dispatches instead of 600).
// The pass1->pass2 dependency (dpsi needs updated psi at +-2 neighbors) is
// resolved in-register: psi is double-buffered and each frame thread
// recomputes its 4 neighbors' psi_new values. Dispatch boundary = grid sync
// (cooperative grid.sync() measured ~69us/step on MI355X due to cross-XCD
// coherence; dispatch boundary is ~5us — R4 post-mortem).

constexpr int NYX  = 400;
constexpr int NS   = 4;
constexpr int NREC = 100;
constexpr int NT   = 300;
constexpr int PAD  = 22;
constexpr int NP   = 444;
constexpr int NP2  = NP * NP;          // 197136
constexpr int SNP2 = NS * NP2;         // 788544
constexpr float DT    = 0.0005f;
constexpr float INVH  = 0.2f;          // 1/DX
constexpr float INVH2 = 0.04f;         // 1/DX^2
constexpr float C1A = 1.0f / 12.0f;
constexpr float C1B = 2.0f / 3.0f;
constexpr float C2A = -1.0f / 12.0f;
constexpr float C2B = 4.0f / 3.0f;
constexpr float C2C = -2.5f;

__device__ __align__(16) float g_wb[2][SNP2];      // bg field ping-pong
__device__ __align__(16) float g_ws[2][SNP2];      // scattered field ping-pong
__device__ __align__(16) float g_psi[2][4][SNP2];  // [buf][py_b,px_b,py_s,px_s]
__device__ __align__(16) float g_zeta[4][SNP2];    // [zy_b,zx_b,zy_s,zx_s]
__device__ float g_v2dt2[NP2];
__device__ float g_bscale[NP2];
__device__ float g_pa[NP];
__device__ float g_pb[NP];
__device__ float g_fbg[NT * NS];
__device__ float g_fsc[NT * NS];
__device__ int   g_spos[2 * NS];
__device__ int   g_mode;               // 1 = bf16 io, 0 = f32 io

__device__ __forceinline__ int clampi(int v, int lo, int hi) {
    return v < lo ? lo : (v > hi ? hi : v);
}
__device__ __forceinline__ float in_ld(const void* p, int i) {
    if (g_mode) return __bfloat162float(((const __hip_bfloat16*)p)[i]);
    return ((const float*)p)[i];
}
__device__ __forceinline__ void out_st(void* p, int i, float v) {
    if (g_mode) ((__hip_bfloat16*)p)[i] = __float2bfloat16(v);
    else        ((float*)p)[i] = v;
}
__device__ __forceinline__ float ld(const float* w, int y, int x) {
    if ((unsigned)y >= (unsigned)NP || (unsigned)x >= (unsigned)NP) return 0.f;
    return w[y * NP + x];
}

__global__ void detect_mode(const void* vptr) {
    if (threadIdx.x == 0 && blockIdx.x == 0) {
        const __hip_bfloat16* p = (const __hip_bfloat16*)vptr;
        int ok = 1;
        for (int i = 0; i < 32; i += 2) {
            float f = __bfloat162float(p[i]);
            if (!(f >= 1000.f && f <= 3000.f)) ok = 0;
        }
        g_mode = ok;
    }
}

__global__ void zero_state() {
    int i = blockIdx.x * blockDim.x + threadIdx.x;
    if (i >= NP2) return;                 // SNP2/4 float4s per array == NP2
    float4 z = make_float4(0.f, 0.f, 0.f, 0.f);
    ((float4*)g_wb[0])[i] = z;  ((float4*)g_wb[1])[i] = z;
    ((float4*)g_ws[0])[i] = z;  ((float4*)g_ws[1])[i] = z;
    #pragma unroll
    for (int b = 0; b < 2; ++b)
        #pragma unroll
        for (int k = 0; k < 4; ++k) ((float4*)g_psi[b][k])[i] = z;
    #pragma unroll
    for (int k = 0; k < 4; ++k) ((float4*)g_zeta[k])[i] = z;
}

__global__ void prep_pad(const void* __restrict__ v, const void* __restrict__ sc) {
    int i = blockIdx.x * blockDim.x + threadIdx.x;
    if (i >= NP2) return;
    int y = i / NP, x = i % NP;
    int vy = clampi(y - PAD, 0, NYX - 1);
    int vx = clampi(x - PAD, 0, NYX - 1);
    float vv = in_ld(v, vy * NYX + vx);
    float vd = vv * DT;
    g_v2dt2[i] = vd * vd;
    float s = 0.f;
    if (y >= PAD && y < PAD + NYX && x >= PAD && x < PAD + NYX)
        s = in_ld(sc, (y - PAD) * NYX + (x - PAD));
    g_bscale[i] = 2.f * vv * s * DT * DT;
    if (i < NP) {
        float fi = (float)i;
        float f1 = fminf(fmaxf((22.f - fi) * 0.05f, 0.f), 1.f);
        float f2 = fminf(fmaxf((fi - 421.f) * 0.05f, 0.f), 1.f);
        float frac = fmaxf(f1, f2);
        float sigma = 259.0408229f * frac * frac;
        const float alpha = 78.53981634f;
        float a = expf(-(sigma + alpha) * DT);
        g_pa[i] = a;
        g_pb[i] = (sigma > 0.f) ? sigma / (sigma + alpha) * (a - 1.f) : 0.f;
    }
}

__global__ void prep_src(const void* __restrict__ amp, const int* __restrict__ sloc,
                         const void* __restrict__ v, const void* __restrict__ sc) {
    int i = blockIdx.x * blockDim.x + threadIdx.x;
    if (i >= NT * NS) return;
    int s = i % NS, t = i / NS;
    int ly = clampi(sloc[s * 2 + 0], 0, NYX - 1);
    int lx = clampi(sloc[s * 2 + 1], 0, NYX - 1);
    float a  = in_ld(amp, s * NT + t);
    float vv = in_ld(v,  ly * NYX + lx);
    float ss = in_ld(sc, ly * NYX + lx);
    g_fbg[i] = -a * vv * vv * DT * DT;
    g_fsc[i] = -2.f * a * vv * ss * DT * DT;
    if (i < NS) {
        g_spos[2 * i]     = ly + PAD;
        g_spos[2 * i + 1] = lx + PAD;
    }
}

// recompute dpsi_y at (y,x): psi_new at y+{-2,-1,1,2} rebuilt from psi_old + w
__device__ __forceinline__ void dpsi_y(const float* wb, const float* wsc,
                                       const float* pob, const float* pos,
                                       int y, int x, float& dpb, float& dps) {
    const int off[4] = {-2, -1, 1, 2};
    float pnb[4], pns[4];
    #pragma unroll
    for (int k = 0; k < 4; ++k) {
        int yy = y + off[k];
        float pbv = ((unsigned)yy < (unsigned)NP) ? g_pb[yy] : 0.f;
        float b_ = 0.f, s_ = 0.f;
        if (pbv != 0.f) {
            float pav = g_pa[yy];
            float dwb = (C1A * ld(wb, yy - 2, x) - C1B * ld(wb, yy - 1, x)
                       + C1B * ld(wb, yy + 1, x) - C1A * ld(wb, yy + 2, x)) * INVH;
            float dws = (C1A * ld(wsc, yy - 2, x) - C1B * ld(wsc, yy - 1, x)
                       + C1B * ld(wsc, yy + 1, x) - C1A * ld(wsc, yy + 2, x)) * INVH;
            b_ = pav * pob[yy * NP + x] + pbv * dwb;
            s_ = pav * pos[yy * NP + x] + pbv * dws;
        }
        pnb[k] = b_; pns[k] = s_;
    }
    dpb = (C1A * pnb[0] - C1B * pnb[1] + C1B * pnb[2] - C1A * pnb[3]) * INVH;
    dps = (C1A * pns[0] - C1B * pns[1] + C1B * pns[2] - C1A * pns[3]) * INVH;
}

__device__ __forceinline__ void dpsi_x(const float* wb, const float* wsc,
                                       const float* pob, const float* pos,
                                       int y, int x, float& dpb, float& dps) {
    const int off[4] = {-2, -1, 1, 2};
    float pnb[4], pns[4];
    #pragma unroll
    for (int k = 0; k < 4; ++k) {
        int xx = x + off[k];
        float pbv = ((unsigned)xx < (unsigned)NP) ? g_pb[xx] : 0.f;
        float b_ = 0.f, s_ = 0.f;
        if (pbv != 0.f) {
            float pav = g_pa[xx];
            float dwb = (C1A * ld(wb, y, xx - 2) - C1B * ld(wb, y, xx - 1)
                       + C1B * ld(wb, y, xx + 1) - C1A * ld(wb, y, xx + 2)) * INVH;
            float dws = (C1A * ld(wsc, y, xx - 2) - C1B * ld(wsc, y, xx - 1)
                       + C1B * ld(wsc, y, xx + 1) - C1A * ld(wsc, y, xx + 2)) * INVH;
            b_ = pav * pob[y * NP + xx] + pbv * dwb;
            s_ = pav * pos[y * NP + xx] + pbv * dws;
        }
        pnb[k] = b_; pns[k] = s_;
    }
    dpb = (C1A * pnb[0] - C1B * pnb[1] + C1B * pnb[2] - C1A * pnb[3]) * INVH;
    dps = (C1A * pns[0] - C1B * pns[1] + C1B * pns[2] - C1A * pns[3]) * INVH;
}

// one fused timestep: psi update (dbuf) + zeta + leapfrog + record t-1
__global__ void __launch_bounds__(448)
step_fused(int t, const int* __restrict__ rloc, const int* __restrict__ rbloc,
           void* __restrict__ out) {
    const int x = threadIdx.x;
    const int y = blockIdx.y;
    const int s = blockIdx.z;
    const int cur = t & 1, nxt = cur ^ 1;

    // record step t-1 from buffer cur (read-only this dispatch): y==0 blocks
    if (t > 0 && y == 0 && x < 2 * NREC) {
        int r = x % NREC;
        bool isbg = x < NREC;
        const int* rl = isbg ? rbloc : rloc;
        int ry = clampi(rl[(s * NREC + r) * 2 + 0], 0, NYX - 1) + PAD;
        int rx = clampi(rl[(s * NREC + r) * 2 + 1], 0, NYX - 1) + PAD;
        const float* w = isbg ? g_wb[cur] : g_ws[cur];
        float val = w[s * NP2 + ry * NP + rx];
        int base = isbg ? (2 * SNP2) : (2 * SNP2 + NS * NREC * NT);
        out_st(out, base + (s * NREC + r) * NT + (t - 1), val);
    }
    if (x >= NP) return;

    const int yx  = y * NP + x;
    const int idx = s * NP2 + yx;
    const float* wb  = g_wb[cur] + s * NP2;
    const float* wsc = g_ws[cur] + s * NP2;

    float wc_b = wb[yx];
    float wc_s = wsc[yx];
    float d2y_b = (C2A * (ld(wb, y - 2, x) + ld(wb, y + 2, x))
                 + C2B * (ld(wb, y - 1, x) + ld(wb, y + 1, x)) + C2C * wc_b) * INVH2;
    float d2x_b = (C2A * (ld(wb, y, x - 2) + ld(wb, y, x + 2))
                 + C2B * (ld(wb, y, x - 1) + ld(wb, y, x + 1)) + C2C * wc_b) * INVH2;
    float d2y_s = (C2A * (ld(wsc, y - 2, x) + ld(wsc, y + 2, x))
                 + C2B * (ld(wsc, y - 1, x) + ld(wsc, y + 1, x)) + C2C * wc_s) * INVH2;
    float d2x_s = (C2A * (ld(wsc, y, x - 2) + ld(wsc, y, x + 2))
                 + C2B * (ld(wsc, y, x - 1) + ld(wsc, y, x + 1)) + C2C * wc_s) * INVH2;

    const float pby = g_pb[y], pbx = g_pb[x];

    float dpy_b = 0.f, dpy_s = 0.f, dpx_b = 0.f, dpx_s = 0.f;
    if (y <= 23 || y >= 420)   // psiy nonzero only rows 0..21, 422..443
        dpsi_y(wb, wsc, g_psi[cur][0] + s * NP2, g_psi[cur][2] + s * NP2,
               y, x, dpy_b, dpy_s);
    if (x <= 23 || x >= 420)
        dpsi_x(wb, wsc, g_psi[cur][1] + s * NP2, g_psi[cur][3] + s * NP2,
               y, x, dpx_b, dpx_s);

    // own psi update -> next buffer (frame points only; interior stays 0)
    if (pby != 0.f) {
        float pay = g_pa[y];
        float dwb = (C1A * ld(wb, y - 2, x) - C1B * ld(wb, y - 1, x)
                   + C1B * ld(wb, y + 1, x) - C1A * ld(wb, y + 2, x)) * INVH;
        float dws = (C1A * ld(wsc, y - 2, x) - C1B * ld(wsc, y - 1, x)
                   + C1B * ld(wsc, y + 1, x) - C1A * ld(wsc, y + 2, x)) * INVH;
        g_psi[nxt][0][idx] = pay * g_psi[cur][0][idx] + pby * dwb;
        g_psi[nxt][2][idx] = pay * g_psi[cur][2][idx] + pby * dws;
    }
    if (pbx != 0.f) {
        float pax = g_pa[x];
        float dwb = (C1A * ld(wb, y, x - 2) - C1B * ld(wb, y, x - 1)
                   + C1B * ld(wb, y, x + 1) - C1A * ld(wb, y, x + 2)) * INVH;
        float dws = (C1A * ld(wsc, y, x - 2) - C1B * ld(wsc, y, x - 1)
                   + C1B * ld(wsc, y, x + 1) - C1A * ld(wsc, y, x + 2)) * INVH;
        g_psi[nxt][1][idx] = pax * g_psi[cur][1][idx] + pbx * dwb;
        g_psi[nxt][3][idx] = pax * g_psi[cur][3][idx] + pbx * dws;
    }

    // zeta (in-place, own point only)
    float zy_b = 0.f, zy_s = 0.f, zx_b = 0.f, zx_s = 0.f;
    if (pby != 0.f) {
        float pay = g_pa[y];
        zy_b = pay * g_zeta[0][idx] + pby * (d2y_b + dpy_b);  g_zeta[0][idx] = zy_b;
        zy_s = pay * g_zeta[2][idx] + pby * (d2y_s + dpy_s);  g_zeta[2][idx] = zy_s;
    }
    if (pbx != 0.f) {
        float pax = g_pa[x];
        zx_b = pax * g_zeta[1][idx] + pbx * (d2x_b + dpx_b);  g_zeta[1][idx] = zx_b;
        zx_s = pax * g_zeta[3][idx] + pbx * (d2x_s + dpx_s);  g_zeta[3][idx] = zx_s;
    }

    float lap_b = d2y_b + d2x_b + dpy_b + dpx_b + zy_b + zx_b;
    float lap_s = d2y_s + d2x_s + dpy_s + dpx_s + zy_s + zx_s;
    float v2 = g_v2dt2[yx];
    float* wpb = g_wb[nxt] + s * NP2;   // holds w_{t-1}, becomes w_{t+1}
    float* wps = g_ws[nxt] + s * NP2;
    float wn_b = v2 * lap_b + 2.f * wc_b - wpb[yx];
    float wn_s = v2 * lap_s + 2.f * wc_s - wps[yx] + g_bscale[yx] * lap_b;
    if (y == g_spos[2 * s] && x == g_spos[2 * s + 1]) {
        wn_b += g_fbg[t * NS + s];
        wn_s += g_fsc[t * NS + s];
    }
    wpb[yx] = wn_b;
    wps[yx] = wn_s;
}

__global__ void finalize(const int* __restrict__ rloc, const int* __restrict__ rbloc,
                         void* __restrict__ out) {
    int i = blockIdx.x * blockDim.x + threadIdx.x;
    const float* wb0 = g_wb[0];   // NT even: newest field in buffer 0
    const float* ws0 = g_ws[0];
    if (i < SNP2) {
        out_st(out, i,        wb0[i]);
        out_st(out, SNP2 + i, ws0[i]);
    }
    if (i < 2 * NS * NREC) {      // record last step (t = NT-1)
        bool isbg = i < NS * NREC;
        int k = isbg ? i : i - NS * NREC;
        int s = k / NREC, r = k % NREC;
        const int* rl = isbg ? rbloc : rloc;
        int ry = clampi(rl[(s * NREC + r) * 2 + 0], 0, NYX - 1) + PAD;
        int rx = clampi(rl[(s * NREC + r) * 2 + 1], 0, NYX - 1) + PAD;
        const float* w = isbg ? wb0 : ws0;
        float val = w[s * NP2 + ry * NP + rx];
        int base = isbg ? (2 * SNP2) : (2 * SNP2 + NS * NREC * NT);
        out_st(out, base + (s * NREC + r) * NT + (NT - 1), val);
    }
}

extern "C" void kernel_launch(void* const* d_in, const int* in_sizes, int n_in,
                              void* d_out, int out_size, void* d_ws, size_t ws_size,
                              hipStream_t stream) {
    const void* v   = d_in[0];
    const void* sc  = d_in[1];
    const void* amp = d_in[2];
    const int* sloc  = (const int*)d_in[3];
    const int* rloc  = (const int*)d_in[4];
    const int* rbloc = (const int*)d_in[5];

    detect_mode<<<1, 64, 0, stream>>>(v);
    zero_state<<<(NP2 + 255) / 256, 256, 0, stream>>>();
    prep_pad<<<(NP2 + 255) / 256, 256, 0, stream>>>(v, sc);
    prep_src<<<(NT * NS + 255) / 256, 256, 0, stream>>>(amp, sloc, v, sc);

    dim3 grid(1, NP, NS);
    for (int t = 0; t < NT; ++t)
        step_fused<<<grid, 448, 0, stream>>>(t, rloc, rbloc, d_out);

    finalize<<<(SNP2 + 255) / 256, 256, 0, stream>>>(rloc, rbloc, d_out);
}

// Round 6
// 4868.693 us; speedup vs baseline: 4.2366x; 1.7869x over previous
//
#include <hip/hip_runtime.h>
#include <hip/hip_bf16.h>

// ScalarBorn: 4th-order FD scalar wave + Born scattering with CPML, MI355X.
// R6: one fused kernel per step (300 stencil dispatches). Halo recompute
// restructured: dpsi_x comes from an LDS row buffer of own-point psi_x_new
// (zero recompute); dpsi_y via a 9-row register column, only on the 44
// y-frame rows (block-uniform branch). R5's naive halo recompute (~70
// redundant loads/frame thread) was 29us/step; R4 showed grid.sync costs
// ~69us/step on MI355X (cross-XCD coherence), so dispatch boundaries stay.

constexpr int NYX  = 400;
constexpr int NS   = 4;
constexpr int NREC = 100;
constexpr int NT   = 300;
constexpr int PAD  = 22;
constexpr int NP   = 444;
constexpr int NP2  = NP * NP;          // 197136
constexpr int SNP2 = NS * NP2;         // 788544
constexpr float DT    = 0.0005f;
constexpr float INVH  = 0.2f;          // 1/DX
constexpr float INVH2 = 0.04f;         // 1/DX^2
constexpr float C1A = 1.0f / 12.0f;
constexpr float C1B = 2.0f / 3.0f;
constexpr float C2A = -1.0f / 12.0f;
constexpr float C2B = 4.0f / 3.0f;
constexpr float C2C = -2.5f;

__device__ __align__(16) float g_wb[2][SNP2];      // bg field ping-pong
__device__ __align__(16) float g_ws[2][SNP2];      // scattered field ping-pong
__device__ __align__(16) float g_psi[2][4][SNP2];  // [buf][py_b,px_b,py_s,px_s]
__device__ __align__(16) float g_zeta[4][SNP2];    // [zy_b,zx_b,zy_s,zx_s]
__device__ float g_v2dt2[NP2];
__device__ float g_bscale[NP2];
__device__ float g_pa[NP];
__device__ float g_pb[NP];
__device__ float g_fbg[NT * NS];
__device__ float g_fsc[NT * NS];
__device__ int   g_spos[2 * NS];
__device__ int   g_mode;               // 1 = bf16 io, 0 = f32 io

__device__ __forceinline__ int clampi(int v, int lo, int hi) {
    return v < lo ? lo : (v > hi ? hi : v);
}
__device__ __forceinline__ float in_ld(const void* p, int i) {
    if (g_mode) return __bfloat162float(((const __hip_bfloat16*)p)[i]);
    return ((const float*)p)[i];
}
__device__ __forceinline__ void out_st(void* p, int i, float v) {
    if (g_mode) ((__hip_bfloat16*)p)[i] = __float2bfloat16(v);
    else        ((float*)p)[i] = v;
}
__device__ __forceinline__ float ld(const float* w, int y, int x) {
    if ((unsigned)y >= (unsigned)NP || (unsigned)x >= (unsigned)NP) return 0.f;
    return w[y * NP + x];
}

__global__ void detect_mode(const void* vptr) {
    if (threadIdx.x == 0 && blockIdx.x == 0) {
        const __hip_bfloat16* p = (const __hip_bfloat16*)vptr;
        int ok = 1;
        for (int i = 0; i < 32; i += 2) {
            float f = __bfloat162float(p[i]);
            if (!(f >= 1000.f && f <= 3000.f)) ok = 0;
        }
        g_mode = ok;
    }
}

__global__ void zero_state() {
    int i = blockIdx.x * blockDim.x + threadIdx.x;
    if (i >= NP2) return;                 // SNP2/4 float4s per array == NP2
    float4 z = make_float4(0.f, 0.f, 0.f, 0.f);
    ((float4*)g_wb[0])[i] = z;  ((float4*)g_wb[1])[i] = z;
    ((float4*)g_ws[0])[i] = z;  ((float4*)g_ws[1])[i] = z;
    #pragma unroll
    for (int b = 0; b < 2; ++b)
        #pragma unroll
        for (int k = 0; k < 4; ++k) ((float4*)g_psi[b][k])[i] = z;
    #pragma unroll
    for (int k = 0; k < 4; ++k) ((float4*)g_zeta[k])[i] = z;
}

__global__ void prep_pad(const void* __restrict__ v, const void* __restrict__ sc) {
    int i = blockIdx.x * blockDim.x + threadIdx.x;
    if (i >= NP2) return;
    int y = i / NP, x = i % NP;
    int vy = clampi(y - PAD, 0, NYX - 1);
    int vx = clampi(x - PAD, 0, NYX - 1);
    float vv = in_ld(v, vy * NYX + vx);
    float vd = vv * DT;
    g_v2dt2[i] = vd * vd;
    float s = 0.f;
    if (y >= PAD && y < PAD + NYX && x >= PAD && x < PAD + NYX)
        s = in_ld(sc, (y - PAD) * NYX + (x - PAD));
    g_bscale[i] = 2.f * vv * s * DT * DT;
    if (i < NP) {
        float fi = (float)i;
        float f1 = fminf(fmaxf((22.f - fi) * 0.05f, 0.f), 1.f);
        float f2 = fminf(fmaxf((fi - 421.f) * 0.05f, 0.f), 1.f);
        float frac = fmaxf(f1, f2);
        float sigma = 259.0408229f * frac * frac;
        const float alpha = 78.53981634f;
        float a = expf(-(sigma + alpha) * DT);
        g_pa[i] = a;
        g_pb[i] = (sigma > 0.f) ? sigma / (sigma + alpha) * (a - 1.f) : 0.f;
    }
}

__global__ void prep_src(const void* __restrict__ amp, const int* __restrict__ sloc,
                         const void* __restrict__ v, const void* __restrict__ sc) {
    int i = blockIdx.x * blockDim.x + threadIdx.x;
    if (i >= NT * NS) return;
    int s = i % NS, t = i / NS;
    int ly = clampi(sloc[s * 2 + 0], 0, NYX - 1);
    int lx = clampi(sloc[s * 2 + 1], 0, NYX - 1);
    float a  = in_ld(amp, s * NT + t);
    float vv = in_ld(v,  ly * NYX + lx);
    float ss = in_ld(sc, ly * NYX + lx);
    g_fbg[i] = -a * vv * vv * DT * DT;
    g_fsc[i] = -2.f * a * vv * ss * DT * DT;
    if (i < NS) {
        g_spos[2 * i]     = ly + PAD;
        g_spos[2 * i + 1] = lx + PAD;
    }
}

// one fused timestep. Block = one row y of one shot s.
__global__ void __launch_bounds__(448)
step_fused(int t, const int* __restrict__ rloc, const int* __restrict__ rbloc,
           void* __restrict__ out) {
    const int x = threadIdx.x;
    const int y = blockIdx.y;
    const int s = blockIdx.z;
    const int cur = t & 1, nxt = cur ^ 1;
    __shared__ float lpxb[448], lpxs[448];   // own-point psi_x_new row buffer

    // record step t-1 from buffer cur (read-only this dispatch): y==0 blocks
    if (t > 0 && y == 0 && x < 2 * NREC) {
        int r = x % NREC;
        bool isbg = x < NREC;
        const int* rl = isbg ? rbloc : rloc;
        int ry = clampi(rl[(s * NREC + r) * 2 + 0], 0, NYX - 1) + PAD;
        int rx = clampi(rl[(s * NREC + r) * 2 + 1], 0, NYX - 1) + PAD;
        const float* w = isbg ? g_wb[cur] : g_ws[cur];
        float val = w[s * NP2 + ry * NP + rx];
        int base = isbg ? (2 * SNP2) : (2 * SNP2 + NS * NREC * NT);
        out_st(out, base + (s * NREC + r) * NT + (t - 1), val);
    }

    const bool active = x < NP;
    const int yx  = y * NP + x;
    const int idx = s * NP2 + yx;
    const float* wb  = g_wb[cur] + s * NP2;
    const float* wsc = g_ws[cur] + s * NP2;

    // ---- x direction: d2x + own psi_x_new (inputs shared with d2x) ----
    float pbx = 0.f, pax = 0.f;
    float d2x_b = 0.f, d2x_s = 0.f;
    float psixnb = 0.f, psixns = 0.f;
    if (active) {
        pbx = g_pb[x]; pax = g_pa[x];
        float wxb[5], wxs[5];
        #pragma unroll
        for (int k = 0; k < 5; ++k) {
            wxb[k] = ld(wb,  y, x - 2 + k);
            wxs[k] = ld(wsc, y, x - 2 + k);
        }
        d2x_b = (C2A * (wxb[0] + wxb[4]) + C2B * (wxb[1] + wxb[3]) + C2C * wxb[2]) * INVH2;
        d2x_s = (C2A * (wxs[0] + wxs[4]) + C2B * (wxs[1] + wxs[3]) + C2C * wxs[2]) * INVH2;
        if (pbx != 0.f) {
            float dwx_b = (C1A * wxb[0] - C1B * wxb[1] + C1B * wxb[3] - C1A * wxb[4]) * INVH;
            float dwx_s = (C1A * wxs[0] - C1B * wxs[1] + C1B * wxs[3] - C1A * wxs[4]) * INVH;
            psixnb = pax * g_psi[cur][1][idx] + pbx * dwx_b;
            psixns = pax * g_psi[cur][3][idx] + pbx * dwx_s;
            g_psi[nxt][1][idx] = psixnb;
            g_psi[nxt][3][idx] = psixns;
        }
    }
    lpxb[x] = psixnb;
    lpxs[x] = psixns;
    __syncthreads();
    if (!active) return;

    // ---- y direction ----
    const float pby = g_pb[y];               // block-uniform
    float d2y_b, d2y_s;
    float dpy_b = 0.f, dpy_s = 0.f;
    if (y <= 23 || y >= 420) {               // 44 y-frame rows + 4 deriv rows
        float wyb[9], wys[9];                // rows y-4..y+4, column x
        #pragma unroll
        for (int k = 0; k < 9; ++k) {
            wyb[k] = ld(wb,  y - 4 + k, x);
            wys[k] = ld(wsc, y - 4 + k, x);
        }
        d2y_b = (C2A * (wyb[2] + wyb[6]) + C2B * (wyb[3] + wyb[5]) + C2C * wyb[4]) * INVH2;
        d2y_s = (C2A * (wys[2] + wys[6]) + C2B * (wys[3] + wys[5]) + C2C * wys[4]) * INVH2;
        // psi_y_new at rows y-2..y+2 from register column (k -> row y-2+k)
        float pnb[5], pns[5];
        #pragma unroll
        for (int k = 0; k < 5; ++k) {
            int yy = y - 2 + k;
            float pbv = ((unsigned)yy < (unsigned)NP) ? g_pb[yy] : 0.f;  // uniform
            float b_ = 0.f, s_ = 0.f;
            if (pbv != 0.f) {
                float pav = g_pa[yy];
                float db = (C1A * wyb[k] - C1B * wyb[k + 1]
                          + C1B * wyb[k + 3] - C1A * wyb[k + 4]) * INVH;
                float ds = (C1A * wys[k] - C1B * wys[k + 1]
                          + C1B * wys[k + 3] - C1A * wys[k + 4]) * INVH;
                b_ = pav * g_psi[cur][0][s * NP2 + yy * NP + x] + pbv * db;
                s_ = pav * g_psi[cur][2][s * NP2 + yy * NP + x] + pbv * ds;
            }
            pnb[k] = b_; pns[k] = s_;
        }
        dpy_b = (C1A * pnb[0] - C1B * pnb[1] + C1B * pnb[3] - C1A * pnb[4]) * INVH;
        dpy_s = (C1A * pns[0] - C1B * pns[1] + C1B * pns[3] - C1A * pns[4]) * INVH;
        if (pby != 0.f) {                    // own psi_y_new -> next buffer
            g_psi[nxt][0][idx] = pnb[2];
            g_psi[nxt][2][idx] = pns[2];
        }
    } else {                                 // interior rows: light path
        float wyb[5], wys[5];
        #pragma unroll
        for (int k = 0; k < 5; ++k) {
            wyb[k] = ld(wb,  y - 2 + k, x);
            wys[k] = ld(wsc, y - 2 + k, x);
        }
        d2y_b = (C2A * (wyb[0] + wyb[4]) + C2B * (wyb[1] + wyb[3]) + C2C * wyb[2]) * INVH2;
        d2y_s = (C2A * (wys[0] + wys[4]) + C2B * (wys[1] + wys[3]) + C2C * wys[2]) * INVH2;
    }

    // ---- dpsi_x from LDS (4-tap, zero-padded) ----
    float dpx_b = 0.f, dpx_s = 0.f;
    if (x <= 23 || x >= 420) {
        float pm2b = (x >= 2) ? lpxb[x - 2] : 0.f;
        float pm1b = (x >= 1) ? lpxb[x - 1] : 0.f;
        float pm2s = (x >= 2) ? lpxs[x - 2] : 0.f;
        float pm1s = (x >= 1) ? lpxs[x - 1] : 0.f;
        dpx_b = (C1A * pm2b - C1B * pm1b + C1B * lpxb[x + 1] - C1A * lpxb[x + 2]) * INVH;
        dpx_s = (C1A * pm2s - C1B * pm1s + C1B * lpxs[x + 1] - C1A * lpxs[x + 2]) * INVH;
    }

    // ---- zeta (in-place, own point only) ----
    float zy_b = 0.f, zy_s = 0.f, zx_b = 0.f, zx_s = 0.f;
    if (pby != 0.f) {
        float pay = g_pa[y];
        zy_b = pay * g_zeta[0][idx] + pby * (d2y_b + dpy_b);  g_zeta[0][idx] = zy_b;
        zy_s = pay * g_zeta[2][idx] + pby * (d2y_s + dpy_s);  g_zeta[2][idx] = zy_s;
    }
    if (pbx != 0.f) {
        zx_b = pax * g_zeta[1][idx] + pbx * (d2x_b + dpx_b);  g_zeta[1][idx] = zx_b;
        zx_s = pax * g_zeta[3][idx] + pbx * (d2x_s + dpx_s);  g_zeta[3][idx] = zx_s;
    }

    // ---- lap + leapfrog + Born + source ----
    float lap_b = d2y_b + d2x_b + dpy_b + dpx_b + zy_b + zx_b;
    float lap_s = d2y_s + d2x_s + dpy_s + dpx_s + zy_s + zx_s;
    float v2 = g_v2dt2[yx];
    float* wpb = g_wb[nxt] + s * NP2;   // holds w_{t-1}, becomes w_{t+1}
    float* wps = g_ws[nxt] + s * NP2;
    float wn_b = v2 * lap_b + 2.f * wb[yx]  - wpb[yx];
    float wn_s = v2 * lap_s + 2.f * wsc[yx] - wps[yx] + g_bscale[yx] * lap_b;
    if (y == g_spos[2 * s] && x == g_spos[2 * s + 1]) {
        wn_b += g_fbg[t * NS + s];
        wn_s += g_fsc[t * NS + s];
    }
    wpb[yx] = wn_b;
    wps[yx] = wn_s;
}

__global__ void finalize(const int* __restrict__ rloc, const int* __restrict__ rbloc,
                         void* __restrict__ out) {
    int i = blockIdx.x * blockDim.x + threadIdx.x;
    const float* wb0 = g_wb[0];   // NT even: newest field in buffer 0
    const float* ws0 = g_ws[0];
    if (i < SNP2) {
        out_st(out, i,        wb0[i]);
        out_st(out, SNP2 + i, ws0[i]);
    }
    if (i < 2 * NS * NREC) {      // record last step (t = NT-1)
        bool isbg = i < NS * NREC;
        int k = isbg ? i : i - NS * NREC;
        int s = k / NREC, r = k % NREC;
        const int* rl = isbg ? rbloc : rloc;
        int ry = clampi(rl[(s * NREC + r) * 2 + 0], 0, NYX - 1) + PAD;
        int rx = clampi(rl[(s * NREC + r) * 2 + 1], 0, NYX - 1) + PAD;
        const float* w = isbg ? wb0 : ws0;
        float val = w[s * NP2 + ry * NP + rx];
        int base = isbg ? (2 * SNP2) : (2 * SNP2 + NS * NREC * NT);
        out_st(out, base + (s * NREC + r) * NT + (NT - 1), val);
    }
}

extern "C" void kernel_launch(void* const* d_in, const int* in_sizes, int n_in,
                              void* d_out, int out_size, void* d_ws, size_t ws_size,
                              hipStream_t stream) {
    const void* v   = d_in[0];
    const void* sc  = d_in[1];
    const void* amp = d_in[2];
    const int* sloc  = (const int*)d_in[3];
    const int* rloc  = (const int*)d_in[4];
    const int* rbloc = (const int*)d_in[5];

    detect_mode<<<1, 64, 0, stream>>>(v);
    zero_state<<<(NP2 + 255) / 256, 256, 0, stream>>>();
    prep_pad<<<(NP2 + 255) / 256, 256, 0, stream>>>(v, sc);
    prep_src<<<(NT * NS + 255) / 256, 256, 0, stream>>>(amp, sloc, v, sc);

    dim3 grid(1, NP, NS);
    for (int t = 0; t < NT; ++t)
        step_fused<<<grid, 448, 0, stream>>>(t, rloc, rbloc, d_out);

    finalize<<<(SNP2 + 255) / 256, 256, 0, stream>>>(rloc, rbloc, d_out);
}

// Round 7
// 4732.024 us; speedup vs baseline: 4.3589x; 1.0289x over previous
//
#include <hip/hip_runtime.h>
#include <hip/hip_bf16.h>

// ScalarBorn: 4th-order FD scalar wave + Born scattering with CPML, MI355X.
// R7: one fused kernel/step (300 dispatches). New vs R6: wavefield rows are
// staged in LDS (zero-padded), so all x-direction stencils (d2x, dw_x) read
// LDS instead of 8 extra global loads/point; psi_x_new is computed from the
// same LDS taps and staged for dpsi_x (2 barriers/step). Interior global
// loads/point: 24 -> 14. grid.sync() rejected (R4: ~69us/step, cross-XCD).

constexpr int NYX  = 400;
constexpr int NS   = 4;
constexpr int NREC = 100;
constexpr int NT   = 300;
constexpr int PAD  = 22;
constexpr int NP   = 444;
constexpr int NP2  = NP * NP;          // 197136
constexpr int SNP2 = NS * NP2;         // 788544
constexpr float DT    = 0.0005f;
constexpr float INVH  = 0.2f;          // 1/DX
constexpr float INVH2 = 0.04f;         // 1/DX^2
constexpr float C1A = 1.0f / 12.0f;
constexpr float C1B = 2.0f / 3.0f;
constexpr float C2A = -1.0f / 12.0f;
constexpr float C2B = 4.0f / 3.0f;
constexpr float C2C = -2.5f;

__device__ __align__(16) float g_wb[2][SNP2];      // bg field ping-pong
__device__ __align__(16) float g_ws[2][SNP2];      // scattered field ping-pong
__device__ __align__(16) float g_psi[2][4][SNP2];  // [buf][py_b,px_b,py_s,px_s]
__device__ __align__(16) float g_zeta[4][SNP2];    // [zy_b,zx_b,zy_s,zx_s]
__device__ float g_v2dt2[NP2];
__device__ float g_bscale[NP2];
__device__ float g_pa[NP];
__device__ float g_pb[NP];
__device__ float g_fbg[NT * NS];
__device__ float g_fsc[NT * NS];
__device__ int   g_spos[2 * NS];
__device__ int   g_mode;               // 1 = bf16 io, 0 = f32 io

__device__ __forceinline__ int clampi(int v, int lo, int hi) {
    return v < lo ? lo : (v > hi ? hi : v);
}
__device__ __forceinline__ float in_ld(const void* p, int i) {
    if (g_mode) return __bfloat162float(((const __hip_bfloat16*)p)[i]);
    return ((const float*)p)[i];
}
__device__ __forceinline__ void out_st(void* p, int i, float v) {
    if (g_mode) ((__hip_bfloat16*)p)[i] = __float2bfloat16(v);
    else        ((float*)p)[i] = v;
}
__device__ __forceinline__ float ld(const float* w, int y, int x) {
    if ((unsigned)y >= (unsigned)NP || (unsigned)x >= (unsigned)NP) return 0.f;
    return w[y * NP + x];
}

__global__ void detect_mode(const void* vptr) {
    if (threadIdx.x == 0 && blockIdx.x == 0) {
        const __hip_bfloat16* p = (const __hip_bfloat16*)vptr;
        int ok = 1;
        for (int i = 0; i < 32; i += 2) {
            float f = __bfloat162float(p[i]);
            if (!(f >= 1000.f && f <= 3000.f)) ok = 0;
        }
        g_mode = ok;
    }
}

__global__ void zero_state() {
    int i = blockIdx.x * blockDim.x + threadIdx.x;
    if (i >= NP2) return;                 // SNP2/4 float4s per array == NP2
    float4 z = make_float4(0.f, 0.f, 0.f, 0.f);
    ((float4*)g_wb[0])[i] = z;  ((float4*)g_wb[1])[i] = z;
    ((float4*)g_ws[0])[i] = z;  ((float4*)g_ws[1])[i] = z;
    #pragma unroll
    for (int b = 0; b < 2; ++b)
        #pragma unroll
        for (int k = 0; k < 4; ++k) ((float4*)g_psi[b][k])[i] = z;
    #pragma unroll
    for (int k = 0; k < 4; ++k) ((float4*)g_zeta[k])[i] = z;
}

__global__ void prep_pad(const void* __restrict__ v, const void* __restrict__ sc) {
    int i = blockIdx.x * blockDim.x + threadIdx.x;
    if (i >= NP2) return;
    int y = i / NP, x = i % NP;
    int vy = clampi(y - PAD, 0, NYX - 1);
    int vx = clampi(x - PAD, 0, NYX - 1);
    float vv = in_ld(v, vy * NYX + vx);
    float vd = vv * DT;
    g_v2dt2[i] = vd * vd;
    float s = 0.f;
    if (y >= PAD && y < PAD + NYX && x >= PAD && x < PAD + NYX)
        s = in_ld(sc, (y - PAD) * NYX + (x - PAD));
    g_bscale[i] = 2.f * vv * s * DT * DT;
    if (i < NP) {
        float fi = (float)i;
        float f1 = fminf(fmaxf((22.f - fi) * 0.05f, 0.f), 1.f);
        float f2 = fminf(fmaxf((fi - 421.f) * 0.05f, 0.f), 1.f);
        float frac = fmaxf(f1, f2);
        float sigma = 259.0408229f * frac * frac;
        const float alpha = 78.53981634f;
        float a = expf(-(sigma + alpha) * DT);
        g_pa[i] = a;
        g_pb[i] = (sigma > 0.f) ? sigma / (sigma + alpha) * (a - 1.f) : 0.f;
    }
}

__global__ void prep_src(const void* __restrict__ amp, const int* __restrict__ sloc,
                         const void* __restrict__ v, const void* __restrict__ sc) {
    int i = blockIdx.x * blockDim.x + threadIdx.x;
    if (i >= NT * NS) return;
    int s = i % NS, t = i / NS;
    int ly = clampi(sloc[s * 2 + 0], 0, NYX - 1);
    int lx = clampi(sloc[s * 2 + 1], 0, NYX - 1);
    float a  = in_ld(amp, s * NT + t);
    float vv = in_ld(v,  ly * NYX + lx);
    float ss = in_ld(sc, ly * NYX + lx);
    g_fbg[i] = -a * vv * vv * DT * DT;
    g_fsc[i] = -2.f * a * vv * ss * DT * DT;
    if (i < NS) {
        g_spos[2 * i]     = ly + PAD;
        g_spos[2 * i + 1] = lx + PAD;
    }
}

// one fused timestep. Block = one row y of one shot s. 448 threads.
__global__ void __launch_bounds__(448)
step_fused(int t, const int* __restrict__ rloc, const int* __restrict__ rbloc,
           void* __restrict__ out) {
    const int x = threadIdx.x;
    const int y = blockIdx.y;
    const int s = blockIdx.z;
    const int cur = t & 1, nxt = cur ^ 1;
    // zero-padded row buffers: logical col c at index c+2; [0,2) and [446,452) are 0
    __shared__ float swb[452], sws[452];     // w rows
    __shared__ float spxb[452], spxs[452];   // psi_x_new rows

    // record step t-1 from buffer cur (read-only this dispatch): y==0 blocks
    if (t > 0 && y == 0 && x < 2 * NREC) {
        int r = x % NREC;
        bool isbg = x < NREC;
        const int* rl = isbg ? rbloc : rloc;
        int ry = clampi(rl[(s * NREC + r) * 2 + 0], 0, NYX - 1) + PAD;
        int rx = clampi(rl[(s * NREC + r) * 2 + 1], 0, NYX - 1) + PAD;
        const float* w = isbg ? g_wb[cur] : g_ws[cur];
        float val = w[s * NP2 + ry * NP + rx];
        int base = isbg ? (2 * SNP2) : (2 * SNP2 + NS * NREC * NT);
        out_st(out, base + (s * NREC + r) * NT + (t - 1), val);
    }

    const bool active = x < NP;
    const int yx  = y * NP + x;
    const int idx = s * NP2 + yx;
    const float* wb  = g_wb[cur] + s * NP2;
    const float* wsc = g_ws[cur] + s * NP2;
    const int lx = x + 2;

    // ---- stage own w values into LDS ----
    float wbv = 0.f, wsv = 0.f;
    if (active) { wbv = wb[yx]; wsv = wsc[yx]; }
    swb[lx] = wbv;  sws[lx] = wsv;
    if (x < 2)    { swb[x] = 0.f;     sws[x] = 0.f; }
    if (x >= 446) { swb[x + 4] = 0.f; sws[x + 4] = 0.f; }
    __syncthreads();

    // ---- x stencils from LDS + own psi_x update ----
    float pbx = 0.f, pax = 0.f;
    float d2x_b = 0.f, d2x_s = 0.f;
    float psixnb = 0.f, psixns = 0.f;
    if (active) {
        pbx = g_pb[x]; pax = g_pa[x];
        float bm2 = swb[lx - 2], bm1 = swb[lx - 1], bp1 = swb[lx + 1], bp2 = swb[lx + 2];
        float sm2 = sws[lx - 2], sm1 = sws[lx - 1], sp1 = sws[lx + 1], sp2 = sws[lx + 2];
        d2x_b = (C2A * (bm2 + bp2) + C2B * (bm1 + bp1) + C2C * wbv) * INVH2;
        d2x_s = (C2A * (sm2 + sp2) + C2B * (sm1 + sp1) + C2C * wsv) * INVH2;
        if (pbx != 0.f) {
            float dwx_b = (C1A * bm2 - C1B * bm1 + C1B * bp1 - C1A * bp2) * INVH;
            float dwx_s = (C1A * sm2 - C1B * sm1 + C1B * sp1 - C1A * sp2) * INVH;
            psixnb = pax * g_psi[cur][1][idx] + pbx * dwx_b;
            psixns = pax * g_psi[cur][3][idx] + pbx * dwx_s;
            g_psi[nxt][1][idx] = psixnb;
            g_psi[nxt][3][idx] = psixns;
        }
    }
    spxb[lx] = psixnb;  spxs[lx] = psixns;
    if (x < 2)    { spxb[x] = 0.f;     spxs[x] = 0.f; }
    if (x >= 446) { spxb[x + 4] = 0.f; spxs[x + 4] = 0.f; }
    __syncthreads();
    if (!active) return;

    // ---- y direction ----
    const float pby = g_pb[y];               // block-uniform
    float d2y_b, d2y_s;
    float dpy_b = 0.f, dpy_s = 0.f;
    if (y <= 23 || y >= 420) {               // y-frame + deriv-of-frame rows
        float wyb[9], wys[9];                // rows y-4..y+4, column x
        #pragma unroll
        for (int k = 0; k < 9; ++k) {
            if (k == 4) { wyb[4] = wbv; wys[4] = wsv; }
            else        { wyb[k] = ld(wb, y - 4 + k, x); wys[k] = ld(wsc, y - 4 + k, x); }
        }
        d2y_b = (C2A * (wyb[2] + wyb[6]) + C2B * (wyb[3] + wyb[5]) + C2C * wyb[4]) * INVH2;
        d2y_s = (C2A * (wys[2] + wys[6]) + C2B * (wys[3] + wys[5]) + C2C * wys[4]) * INVH2;
        // psi_y_new at rows y-2..y+2 from register column (k -> row y-2+k)
        float pnb[5], pns[5];
        #pragma unroll
        for (int k = 0; k < 5; ++k) {
            int yy = y - 2 + k;
            float pbv = ((unsigned)yy < (unsigned)NP) ? g_pb[yy] : 0.f;  // uniform
            float b_ = 0.f, s_ = 0.f;
            if (pbv != 0.f) {
                float pav = g_pa[yy];
                float db = (C1A * wyb[k] - C1B * wyb[k + 1]
                          + C1B * wyb[k + 3] - C1A * wyb[k + 4]) * INVH;
                float ds = (C1A * wys[k] - C1B * wys[k + 1]
                          + C1B * wys[k + 3] - C1A * wys[k + 4]) * INVH;
                b_ = pav * g_psi[cur][0][s * NP2 + yy * NP + x] + pbv * db;
                s_ = pav * g_psi[cur][2][s * NP2 + yy * NP + x] + pbv * ds;
            }
            pnb[k] = b_; pns[k] = s_;
        }
        dpy_b = (C1A * pnb[0] - C1B * pnb[1] + C1B * pnb[3] - C1A * pnb[4]) * INVH;
        dpy_s = (C1A * pns[0] - C1B * pns[1] + C1B * pns[3] - C1A * pns[4]) * INVH;
        if (pby != 0.f) {                    // own psi_y_new -> next buffer
            g_psi[nxt][0][idx] = pnb[2];
            g_psi[nxt][2][idx] = pns[2];
        }
    } else {                                 // interior rows: light path
        float bm2 = ld(wb, y - 2, x), bm1 = ld(wb, y - 1, x);
        float bp1 = ld(wb, y + 1, x), bp2 = ld(wb, y + 2, x);
        float sm2 = ld(wsc, y - 2, x), sm1 = ld(wsc, y - 1, x);
        float sp1 = ld(wsc, y + 1, x), sp2 = ld(wsc, y + 2, x);
        d2y_b = (C2A * (bm2 + bp2) + C2B * (bm1 + bp1) + C2C * wbv) * INVH2;
        d2y_s = (C2A * (sm2 + sp2) + C2B * (sm1 + sp1) + C2C * wsv) * INVH2;
    }

    // ---- dpsi_x from LDS psi_x_new buffer (4-tap, zero-padded) ----
    float dpx_b = 0.f, dpx_s = 0.f;
    if (x <= 23 || x >= 420) {
        dpx_b = (C1A * spxb[lx - 2] - C1B * spxb[lx - 1]
               + C1B * spxb[lx + 1] - C1A * spxb[lx + 2]) * INVH;
        dpx_s = (C1A * spxs[lx - 2] - C1B * spxs[lx - 1]
               + C1B * spxs[lx + 1] - C1A * spxs[lx + 2]) * INVH;
    }

    // ---- zeta (in-place, own point only) ----
    float zy_b = 0.f, zy_s = 0.f, zx_b = 0.f, zx_s = 0.f;
    if (pby != 0.f) {
        float pay = g_pa[y];
        zy_b = pay * g_zeta[0][idx] + pby * (d2y_b + dpy_b);  g_zeta[0][idx] = zy_b;
        zy_s = pay * g_zeta[2][idx] + pby * (d2y_s + dpy_s);  g_zeta[2][idx] = zy_s;
    }
    if (pbx != 0.f) {
        zx_b = pax * g_zeta[1][idx] + pbx * (d2x_b + dpx_b);  g_zeta[1][idx] = zx_b;
        zx_s = pax * g_zeta[3][idx] + pbx * (d2x_s + dpx_s);  g_zeta[3][idx] = zx_s;
    }

    // ---- lap + leapfrog + Born + source ----
    float lap_b = d2y_b + d2x_b + dpy_b + dpx_b + zy_b + zx_b;
    float lap_s = d2y_s + d2x_s + dpy_s + dpx_s + zy_s + zx_s;
    float v2 = g_v2dt2[yx];
    float* wpb = g_wb[nxt] + s * NP2;   // holds w_{t-1}, becomes w_{t+1}
    float* wps = g_ws[nxt] + s * NP2;
    float wn_b = v2 * lap_b + 2.f * wbv - wpb[yx];
    float wn_s = v2 * lap_s + 2.f * wsv - wps[yx] + g_bscale[yx] * lap_b;
    if (y == g_spos[2 * s] && x == g_spos[2 * s + 1]) {
        wn_b += g_fbg[t * NS + s];
        wn_s += g_fsc[t * NS + s];
    }
    wpb[yx] = wn_b;
    wps[yx] = wn_s;
}

__global__ void finalize(const int* __restrict__ rloc, const int* __restrict__ rbloc,
                         void* __restrict__ out) {
    int i = blockIdx.x * blockDim.x + threadIdx.x;
    const float* wb0 = g_wb[0];   // NT even: newest field in buffer 0
    const float* ws0 = g_ws[0];
    if (i < SNP2) {
        out_st(out, i,        wb0[i]);
        out_st(out, SNP2 + i, ws0[i]);
    }
    if (i < 2 * NS * NREC) {      // record last step (t = NT-1)
        bool isbg = i < NS * NREC;
        int k = isbg ? i : i - NS * NREC;
        int s = k / NREC, r = k % NREC;
        const int* rl = isbg ? rbloc : rloc;
        int ry = clampi(rl[(s * NREC + r) * 2 + 0], 0, NYX - 1) + PAD;
        int rx = clampi(rl[(s * NREC + r) * 2 + 1], 0, NYX - 1) + PAD;
        const float* w = isbg ? wb0 : ws0;
        float val = w[s * NP2 + ry * NP + rx];
        int base = isbg ? (2 * SNP2) : (2 * SNP2 + NS * NREC * NT);
        out_st(out, base + (s * NREC + r) * NT + (NT - 1), val);
    }
}

extern "C" void kernel_launch(void* const* d_in, const int* in_sizes, int n_in,
                              void* d_out, int out_size, void* d_ws, size_t ws_size,
                              hipStream_t stream) {
    const void* v   = d_in[0];
    const void* sc  = d_in[1];
    const void* amp = d_in[2];
    const int* sloc  = (const int*)d_in[3];
    const int* rloc  = (const int*)d_in[4];
    const int* rbloc = (const int*)d_in[5];

    detect_mode<<<1, 64, 0, stream>>>(v);
    zero_state<<<(NP2 + 255) / 256, 256, 0, stream>>>();
    prep_pad<<<(NP2 + 255) / 256, 256, 0, stream>>>(v, sc);
    prep_src<<<(NT * NS + 255) / 256, 256, 0, stream>>>(amp, sloc, v, sc);

    dim3 grid(1, NP, NS);
    for (int t = 0; t < NT; ++t)
        step_fused<<<grid, 448, 0, stream>>>(t, rloc, rbloc, d_out);

    finalize<<<(SNP2 + 255) / 256, 256, 0, stream>>>(rloc, rbloc, d_out);
}